// Round 3
// baseline (167.138 us; speedup 1.0000x reference)
//
#include <hip/hip_runtime.h>

// DeepDFTinv message block: B=2, P=4096, A=96, G=1, F=32, E=20
#define NB   2
#define NP   4096
#define NA   96
#define NF   32
#define NE   20
#define NBP  (NB*NP)

typedef __attribute__((ext_vector_type(8)))  short bf16x8;   // MFMA A/B frag (4 VGPRs)
typedef __attribute__((ext_vector_type(16))) float f32x16;   // 32x32 MFMA C/D frag

union Frag { bf16x8 v; int i[4]; };

// single-instruction packed f32->bf16 (RNE), src0 -> low half
__device__ __forceinline__ int cvtpk(float lo, float hi) {
  int r;
  asm("v_cvt_pk_bf16_f32 %0, %1, %2" : "=v"(r) : "v"(lo), "v"(hi));
  return r;
}
// shifted softplus: max(x,0) + log(1 + exp(-|x|)) - ln2  (fast-math forms)
__device__ __forceinline__ float ssp_f(float x) {
  float t = __expf(-fabsf(x));
  return fmaxf(x, 0.0f) + __logf(1.0f + t) - 0.69314718056f;
}
__device__ __forceinline__ f32x16 mfma32(const Frag a, const Frag b, f32x16 c) {
  return __builtin_amdgcn_mfma_f32_32x32x16_bf16(a.v, b.v, c, 0, 0, 0);
}
// C-init from 32-float bias vector (global, L1-hit). rows = (r&3)+8*(r>>2)+4*hw
__device__ __forceinline__ f32x16 ld_bias16(const float* __restrict__ base /* bias + 4*hw */) {
  const float4* p = reinterpret_cast<const float4*>(base);
  float4 q0 = p[0], q1 = p[2], q2 = p[4], q3 = p[6];
  f32x16 c;
  c[0]=q0.x;  c[1]=q0.y;  c[2]=q0.z;  c[3]=q0.w;
  c[4]=q1.x;  c[5]=q1.y;  c[6]=q1.z;  c[7]=q1.w;
  c[8]=q2.x;  c[9]=q2.y;  c[10]=q2.z; c[11]=q2.w;
  c[12]=q3.x; c[13]=q3.y; c[14]=q3.z; c[15]=q3.w;
  return c;
}

// ---------- tiny prep: src = scalar @ Ws + b1n -> d_ws (192 rows only) ----------
__global__ __launch_bounds__(256)
void prep_src(const float* __restrict__ scalar,
              const float* __restrict__ W1n,
              const float* __restrict__ b1n,
              float* __restrict__ src_ws)
{
  int i = blockIdx.x * 256 + threadIdx.x;    // 24*256 = 6144 = 192 rows * 32
  int f  = i & 31;
  int ba = i >> 5;
  const float* x = scalar + ba * NF;
  float a = b1n[f];
#pragma unroll
  for (int k = 0; k < NF; ++k) a = fmaf(x[k], W1n[k * NF + f], a);
  src_ws[i] = a;
}

// ---------- main: 4 waves/block, each wave owns 2 (b,p); no LDS, no barriers ----------
__global__ __launch_bounds__(256, 3)
void fused_main(const float* __restrict__ expansion,
                const float* __restrict__ mask,
                const float* __restrict__ edge_dist,
                const float* __restrict__ W1e,
                const float* __restrict__ b1e,
                const float* __restrict__ W2e,
                const float* __restrict__ b2e,
                const float* __restrict__ W2n,
                const float* __restrict__ b2n,
                const float* __restrict__ sr,
                const float* __restrict__ W1n,
                const float* __restrict__ src_ws,
                float* __restrict__ out)
{
  const int tid  = threadIdx.x;
  const int wid  = tid >> 6;
  const int lane = tid & 63;
  const int col  = lane & 31;    // matrix column (= a / = output n)
  const int hw   = lane >> 5;    // half-wave (k-split)

  // ---- transposed-weight A-fragments (row m = col, k = 8*hw + elem) ----
  Frag a1s0, a1s1, a2s0, a2s1, a3s0, a3s1;
#pragma unroll
  for (int r = 0; r < 4; ++r) {
    const int k0 = 8 * hw + 2 * r;     // k = 0..15
    const int k1 = 16 + k0;            // k = 16..31
    a1s0.i[r] = cvtpk(W1e[k0 * NF + col], W1e[(k0 + 1) * NF + col]);
    {
      float lo = (k1     < NE) ? W1e[k1 * NF + col]       : 0.0f;
      float hi = (k1 + 1 < NE) ? W1e[(k1 + 1) * NF + col] : 0.0f;
      a1s1.i[r] = cvtpk(lo, hi);
    }
    a2s0.i[r] = cvtpk(W2e[k0 * NF + col], W2e[(k0 + 1) * NF + col]);
    a2s1.i[r] = cvtpk(W2e[k1 * NF + col], W2e[(k1 + 1) * NF + col]);
    a3s0.i[r] = cvtpk(W2n[k0 * NF + col], W2n[(k0 + 1) * NF + col]);
    a3s1.i[r] = cvtpk(W2n[k1 * NF + col], W2n[(k1 + 1) * NF + col]);
  }

  // Wt column for on-the-fly tgt: wt[i] = W1n[32 + 16*hw + i][col]
  float wt[16];
#pragma unroll
  for (int i2 = 0; i2 < 16; ++i2) wt[i2] = W1n[(NF + 16 * hw + i2) * NF + col];

#pragma unroll 1
  for (int pi = 0; pi < 2; ++pi) {
    const int bp = blockIdx.x * 8 + wid * 2 + pi;
    const int b  = bp >> 12;               // NP = 4096

    // ---- tgt[f] = sum_k sr[bp][k] * Wt[k][f], computed in-wave ----
    const float* srow = sr + bp * NF + 16 * hw;
    float ts = 0.0f;
#pragma unroll
    for (int i2 = 0; i2 < 16; ++i2) ts = fmaf(srow[i2], wt[i2], ts);
    ts += __shfl_xor(ts, 32, 64);          // both halves now hold tgt[col]
    float tA[8], tB[8];
#pragma unroll
    for (int j = 0; j < 8; ++j) {
      tA[j] = __shfl(ts,      8 * hw + j, 64);   // tgt[8hw + j]
      tB[j] = __shfl(ts, 16 + 8 * hw + j, 64);   // tgt[16 + 8hw + j]
    }

    const float* expb  = expansion + (size_t)bp * (NA * NE);
    const float* maskb = mask      + bp * NA;
    const float* distb = edge_dist + bp * NA;
    const float* srcb  = src_ws    + b * (NA * NF);

    f32x16 acc;
#pragma unroll
    for (int r = 0; r < 16; ++r) acc[r] = 0.0f;

#pragma unroll 1
    for (int t = 0; t < 3; ++t) {
      const int a = t * 32 + col;

      // ---- B1 = expansion^T fragment (k=e, n=a) ----
      const float* ea = expb + a * NE;
      float4 e0 = *reinterpret_cast<const float4*>(ea + 8 * hw);
      float4 e1 = *reinterpret_cast<const float4*>(ea + 8 * hw + 4);
      float4 e2 = *reinterpret_cast<const float4*>(ea + 16);   // e=16..19 (half0 only)
      Frag b1f0, b1f1;
      b1f0.i[0] = cvtpk(e0.x, e0.y);
      b1f0.i[1] = cvtpk(e0.z, e0.w);
      b1f0.i[2] = cvtpk(e1.x, e1.y);
      b1f0.i[3] = cvtpk(e1.z, e1.w);
      b1f1.i[0] = hw ? 0 : cvtpk(e2.x, e2.y);
      b1f1.i[1] = hw ? 0 : cvtpk(e2.z, e2.w);
      b1f1.i[2] = 0;
      b1f1.i[3] = 0;

      // ---- GEMM1: H1^T[j][a] ----
      f32x16 d1 = ld_bias16(b1e + 4 * hw);
      d1 = mfma32(a1s0, b1f0, d1);
      d1 = mfma32(a1s1, b1f1, d1);
#pragma unroll
      for (int r = 0; r < 16; ++r) d1[r] = ssp_f(d1[r]);

      // ---- C-layout f32 -> B-layout bf16 (cvt_pk + permlane32_swap) ----
      int u0 = cvtpk(d1[0],  d1[1]);
      int u1 = cvtpk(d1[2],  d1[3]);
      int u2 = cvtpk(d1[4],  d1[5]);
      int u3 = cvtpk(d1[6],  d1[7]);
      int u4 = cvtpk(d1[8],  d1[9]);
      int u5 = cvtpk(d1[10], d1[11]);
      int u6 = cvtpk(d1[12], d1[13]);
      int u7 = cvtpk(d1[14], d1[15]);
      asm("v_permlane32_swap_b32 %0, %1" : "+v"(u0), "+v"(u2));
      asm("v_permlane32_swap_b32 %0, %1" : "+v"(u1), "+v"(u3));
      asm("v_permlane32_swap_b32 %0, %1" : "+v"(u4), "+v"(u6));
      asm("v_permlane32_swap_b32 %0, %1" : "+v"(u5), "+v"(u7));
      Frag b2f0, b2f1;
      b2f0.i[0] = u0; b2f0.i[1] = u1; b2f0.i[2] = u2; b2f0.i[3] = u3;
      b2f1.i[0] = u4; b2f1.i[1] = u5; b2f1.i[2] = u6; b2f1.i[3] = u7;

      // ---- GEMM2: gates^T[f][a] ----
      f32x16 d2 = ld_bias16(b2e + 4 * hw);
      d2 = mfma32(a2s0, b2f0, d2);
      d2 = mfma32(a2s1, b2f1, d2);

      // mask * cutoff envelope: mk / (1 + exp(5*(d-3.5)))
      const float mk = maskb[a];
      const float dd = distb[a];
      const float z  = __expf(5.0f * (dd - 3.5f));
      const float em = mk * __builtin_amdgcn_rcpf(1.0f + z);

      // ---- nodes B-fragment: ssp(src[a][fh] + tgt[fh]) ----
      const float* sa = srcb + a * NF;
      float4 s0 = *reinterpret_cast<const float4*>(sa + 8 * hw);
      float4 s1 = *reinterpret_cast<const float4*>(sa + 8 * hw + 4);
      float4 s2 = *reinterpret_cast<const float4*>(sa + 16 + 8 * hw);
      float4 s3 = *reinterpret_cast<const float4*>(sa + 16 + 8 * hw + 4);
      Frag b3f0, b3f1;
      b3f0.i[0] = cvtpk(ssp_f(s0.x + tA[0]), ssp_f(s0.y + tA[1]));
      b3f0.i[1] = cvtpk(ssp_f(s0.z + tA[2]), ssp_f(s0.w + tA[3]));
      b3f0.i[2] = cvtpk(ssp_f(s1.x + tA[4]), ssp_f(s1.y + tA[5]));
      b3f0.i[3] = cvtpk(ssp_f(s1.z + tA[6]), ssp_f(s1.w + tA[7]));
      b3f1.i[0] = cvtpk(ssp_f(s2.x + tB[0]), ssp_f(s2.y + tB[1]));
      b3f1.i[1] = cvtpk(ssp_f(s2.z + tB[2]), ssp_f(s2.w + tB[3]));
      b3f1.i[2] = cvtpk(ssp_f(s3.x + tB[4]), ssp_f(s3.y + tB[5]));
      b3f1.i[3] = cvtpk(ssp_f(s3.z + tB[6]), ssp_f(s3.w + tB[7]));

      // ---- GEMM3: nodes^T[fo][a] ----
      f32x16 d3 = ld_bias16(b2n + 4 * hw);
      d3 = mfma32(a3s0, b3f0, d3);
      d3 = mfma32(a3s1, b3f1, d3);

      // ---- out += em * gates ⊙ nodes, summed over a later ----
#pragma unroll
      for (int r = 0; r < 16; ++r) acc[r] = fmaf(em * d2[r], d3[r], acc[r]);
    }

    // reduce over columns a (32 lanes within each half-wave)
#pragma unroll
    for (int m = 1; m <= 16; m <<= 1) {
#pragma unroll
      for (int r = 0; r < 16; ++r) acc[r] += __shfl_xor(acc[r], m, 64);
    }

    // rows for reg-quad q: 8q + 4hw + (0..3) -> contiguous float4
    if (col == 0) {
      float4* o = reinterpret_cast<float4*>(out + bp * NF);
#pragma unroll
      for (int q = 0; q < 4; ++q) {
        float4 v;
        v.x = acc[4 * q];     v.y = acc[4 * q + 1];
        v.z = acc[4 * q + 2]; v.w = acc[4 * q + 3];
        o[2 * q + hw] = v;
      }
    }
  }
}

extern "C" void kernel_launch(void* const* d_in, const int* in_sizes, int n_in,
                              void* d_out, int out_size, void* d_ws, size_t ws_size,
                              hipStream_t stream) {
  const float* scalar    = (const float*)d_in[0];
  const float* sreciever = (const float*)d_in[1];
  const float* expansion = (const float*)d_in[2];
  const float* maskp     = (const float*)d_in[3];
  const float* edist     = (const float*)d_in[4];
  const float* W1e       = (const float*)d_in[5];
  const float* b1e       = (const float*)d_in[6];
  const float* W2e       = (const float*)d_in[7];
  const float* b2e       = (const float*)d_in[8];
  const float* W1n       = (const float*)d_in[9];
  const float* b1n       = (const float*)d_in[10];
  const float* W2n       = (const float*)d_in[11];
  const float* b2n       = (const float*)d_in[12];
  float* out    = (float*)d_out;
  float* src_ws = (float*)d_ws;     // 192*32 floats = 24 KB

  prep_src<<<24, 256, 0, stream>>>(scalar, W1n, b1n, src_ws);
  // 1024 blocks * 4 waves * 2 bp = 8192 = NBP
  fused_main<<<NBP / 8, 256, 0, stream>>>(expansion, maskp, edist,
                                          W1e, b1e, W2e, b2e, W2n, b2n,
                                          sreciever, W1n, src_ws, out);
}

// Round 4
// 149.813 us; speedup vs baseline: 1.1156x; 1.1156x over previous
//
#include <hip/hip_runtime.h>

// DeepDFTinv message block: B=2, P=4096, A=96, G=1, F=32, E=20
#define NB   2
#define NP   4096
#define NA   96
#define NF   32
#define NE   20
#define NBP  (NB*NP)

typedef __attribute__((ext_vector_type(8)))  short bf16x8;   // MFMA A/B frag (4 VGPRs)
typedef __attribute__((ext_vector_type(16))) float f32x16;   // 32x32 MFMA C/D frag

union Frag { bf16x8 v; int i[4]; };

// single-instruction packed f32->bf16 (RNE), src0 -> low half
__device__ __forceinline__ int cvtpk(float lo, float hi) {
  int r;
  asm("v_cvt_pk_bf16_f32 %0, %1, %2" : "=v"(r) : "v"(lo), "v"(hi));
  return r;
}
// shifted softplus: max(x,0) + log(1 + exp(-|x|)) - ln2
__device__ __forceinline__ float ssp_f(float x) {
  float t = __expf(-fabsf(x));
  return fmaxf(x, 0.0f) + __logf(1.0f + t) - 0.69314718056f;
}
__device__ __forceinline__ f32x16 mfma32(const Frag a, const Frag b, f32x16 c) {
  return __builtin_amdgcn_mfma_f32_32x32x16_bf16(a.v, b.v, c, 0, 0, 0);
}
// C-init from 32-float LDS bias vector. rows = (r&3)+8*(r>>2)+4*hw
__device__ __forceinline__ f32x16 ld_bias16(const float* base /* bias + 4*hw */) {
  const float4* p = reinterpret_cast<const float4*>(base);
  float4 q0 = p[0], q1 = p[2], q2 = p[4], q3 = p[6];
  f32x16 c;
  c[0]=q0.x;  c[1]=q0.y;  c[2]=q0.z;  c[3]=q0.w;
  c[4]=q1.x;  c[5]=q1.y;  c[6]=q1.z;  c[7]=q1.w;
  c[8]=q2.x;  c[9]=q2.y;  c[10]=q2.z; c[11]=q2.w;
  c[12]=q3.x; c[13]=q3.y; c[14]=q3.z; c[15]=q3.w;
  return c;
}

// ---------- prep: tgt = sr @ Wt -> d_out (each fused wave reads only its own
// row before overwriting it); src = scalar @ Ws + b1n -> d_ws ----------
__global__ __launch_bounds__(256)
void prep_kernel(const float* __restrict__ scalar,
                 const float* __restrict__ sr,
                 const float* __restrict__ W1n,
                 const float* __restrict__ b1n,
                 float* __restrict__ tgt_out,
                 float* __restrict__ src_ws)
{
  int i = blockIdx.x * 256 + threadIdx.x;   // 1048*256 = (8192+192)*32 exactly
  int f   = i & 31;
  int row = i >> 5;
  const float* x;
  const float* W;
  float acc;
  if (row < NBP) { x = sr + row * NF;            W = W1n + NF * NF; acc = 0.0f;   }
  else           { x = scalar + (row - NBP) * NF; W = W1n;          acc = b1n[f]; }
  float4 xv[8];
#pragma unroll
  for (int q = 0; q < 8; ++q) xv[q] = reinterpret_cast<const float4*>(x)[q];
#pragma unroll
  for (int q = 0; q < 8; ++q) {
    acc = fmaf(xv[q].x, W[(4 * q + 0) * NF + f], acc);
    acc = fmaf(xv[q].y, W[(4 * q + 1) * NF + f], acc);
    acc = fmaf(xv[q].z, W[(4 * q + 2) * NF + f], acc);
    acc = fmaf(xv[q].w, W[(4 * q + 3) * NF + f], acc);
  }
  if (row < NBP) tgt_out[i] = acc;
  else           src_ws[(row - NBP) * NF + f] = acc;
}

// ---------- main: 4 waves/block, each wave owns 2 (b,p) ----------
__global__ __launch_bounds__(256, 3)
void fused_main(const float* __restrict__ expansion,
                const float* __restrict__ mask,
                const float* __restrict__ edge_dist,
                const float* __restrict__ W1e,
                const float* __restrict__ b1e,
                const float* __restrict__ W2e,
                const float* __restrict__ b2e,
                const float* __restrict__ W2n,
                const float* __restrict__ b2n,
                const float* __restrict__ src_ws,
                float* __restrict__ out)
{
  const int tid  = threadIdx.x;
  const int wid  = tid >> 6;
  const int lane = tid & 63;
  const int col  = lane & 31;    // matrix column (= a)
  const int hw   = lane >> 5;    // half-wave (k-split)

  __shared__ __align__(16) float smb[96];   // b1e | b2e | b2n
  if (tid < 32) {
    smb[tid]      = b1e[tid];
    smb[32 + tid] = b2e[tid];
    smb[64 + tid] = b2n[tid];
  }
  __syncthreads();
  const float* biasA = smb      + 4 * hw;
  const float* biasB = smb + 32 + 4 * hw;
  const float* biasC = smb + 64 + 4 * hw;

  // ---- transposed-weight A-fragments (row m = col, k = 8*hw + elem) ----
  Frag a1s0, a1s1, a2s0, a2s1, a3s0, a3s1;
#pragma unroll
  for (int r = 0; r < 4; ++r) {
    const int k0 = 8 * hw + 2 * r;     // k = 0..15
    const int k1 = 16 + k0;            // k = 16..31
    a1s0.i[r] = cvtpk(W1e[k0 * NF + col], W1e[(k0 + 1) * NF + col]);
    {
      float lo = (k1     < NE) ? W1e[k1 * NF + col]       : 0.0f;
      float hi = (k1 + 1 < NE) ? W1e[(k1 + 1) * NF + col] : 0.0f;
      a1s1.i[r] = cvtpk(lo, hi);
    }
    a2s0.i[r] = cvtpk(W2e[k0 * NF + col], W2e[(k0 + 1) * NF + col]);
    a2s1.i[r] = cvtpk(W2e[k1 * NF + col], W2e[(k1 + 1) * NF + col]);
    a3s0.i[r] = cvtpk(W2n[k0 * NF + col], W2n[(k0 + 1) * NF + col]);
    a3s1.i[r] = cvtpk(W2n[k1 * NF + col], W2n[(k1 + 1) * NF + col]);
  }

#pragma unroll 1
  for (int pi = 0; pi < 2; ++pi) {
    const int bp = blockIdx.x * 8 + wid * 2 + pi;
    const int b  = bp >> 12;               // NP = 4096

    // ---- prefetch ALL per-bp HBM streams up front: tgt, expansion, mask, dist ----
    const float* tg = out + bp * NF;       // written by prep_kernel
    float4 t0 = *reinterpret_cast<const float4*>(tg + 8 * hw);
    float4 t1 = *reinterpret_cast<const float4*>(tg + 8 * hw + 4);
    float4 t2 = *reinterpret_cast<const float4*>(tg + 16 + 8 * hw);
    float4 t3 = *reinterpret_cast<const float4*>(tg + 16 + 8 * hw + 4);

    const float* expb  = expansion + (size_t)bp * (NA * NE);
    const float* maskb = mask      + bp * NA;
    const float* distb = edge_dist + bp * NA;
    const float* srcb  = src_ws    + b * (NA * NF);

    float4 ef[3][3];
    float  mk[3], dd[3];
#pragma unroll
    for (int t = 0; t < 3; ++t) {
      const int a = t * 32 + col;
      const float* ea = expb + a * NE;
      ef[t][0] = *reinterpret_cast<const float4*>(ea + 8 * hw);
      ef[t][1] = *reinterpret_cast<const float4*>(ea + 8 * hw + 4);
      ef[t][2] = *reinterpret_cast<const float4*>(ea + 16);   // e=16..19 (hw0 uses)
      mk[t] = maskb[a];
      dd[t] = distb[a];
    }
    float em[3];
#pragma unroll
    for (int t = 0; t < 3; ++t) {
      const float z = __expf(5.0f * (dd[t] - 3.5f));
      em[t] = mk[t] * __builtin_amdgcn_rcpf(1.0f + z);
    }

    f32x16 acc;
#pragma unroll
    for (int r = 0; r < 16; ++r) acc[r] = 0.0f;

#pragma unroll
    for (int t = 0; t < 3; ++t) {
      const int a = t * 32 + col;

      // ---- B1 = expansion^T fragment (k=e, n=a) from prefetched regs ----
      Frag b1f0, b1f1;
      b1f0.i[0] = cvtpk(ef[t][0].x, ef[t][0].y);
      b1f0.i[1] = cvtpk(ef[t][0].z, ef[t][0].w);
      b1f0.i[2] = cvtpk(ef[t][1].x, ef[t][1].y);
      b1f0.i[3] = cvtpk(ef[t][1].z, ef[t][1].w);
      b1f1.i[0] = hw ? 0 : cvtpk(ef[t][2].x, ef[t][2].y);
      b1f1.i[1] = hw ? 0 : cvtpk(ef[t][2].z, ef[t][2].w);
      b1f1.i[2] = 0;
      b1f1.i[3] = 0;

      // ---- GEMM1: H1^T[j][a] ----
      f32x16 d1 = ld_bias16(biasA);
      d1 = mfma32(a1s0, b1f0, d1);
      d1 = mfma32(a1s1, b1f1, d1);
#pragma unroll
      for (int r = 0; r < 16; ++r) d1[r] = ssp_f(d1[r]);

      // ---- C-layout f32 -> B-layout bf16 (cvt_pk + permlane32_swap) ----
      int u0 = cvtpk(d1[0],  d1[1]);
      int u1 = cvtpk(d1[2],  d1[3]);
      int u2 = cvtpk(d1[4],  d1[5]);
      int u3 = cvtpk(d1[6],  d1[7]);
      int u4 = cvtpk(d1[8],  d1[9]);
      int u5 = cvtpk(d1[10], d1[11]);
      int u6 = cvtpk(d1[12], d1[13]);
      int u7 = cvtpk(d1[14], d1[15]);
      asm("v_permlane32_swap_b32 %0, %1" : "+v"(u0), "+v"(u2));
      asm("v_permlane32_swap_b32 %0, %1" : "+v"(u1), "+v"(u3));
      asm("v_permlane32_swap_b32 %0, %1" : "+v"(u4), "+v"(u6));
      asm("v_permlane32_swap_b32 %0, %1" : "+v"(u5), "+v"(u7));
      Frag b2f0, b2f1;
      b2f0.i[0] = u0; b2f0.i[1] = u1; b2f0.i[2] = u2; b2f0.i[3] = u3;
      b2f1.i[0] = u4; b2f1.i[1] = u5; b2f1.i[2] = u6; b2f1.i[3] = u7;

      // ---- GEMM2: gates^T[f][a] ----
      f32x16 d2 = ld_bias16(biasB);
      d2 = mfma32(a2s0, b2f0, d2);
      d2 = mfma32(a2s1, b2f1, d2);

      // ---- nodes B-fragment: ssp(src[a][fh] + tgt[fh]) (src is L1-hot, 24 KB) ----
      const float* sa = srcb + a * NF;
      float4 s0 = *reinterpret_cast<const float4*>(sa + 8 * hw);
      float4 s1 = *reinterpret_cast<const float4*>(sa + 8 * hw + 4);
      float4 s2 = *reinterpret_cast<const float4*>(sa + 16 + 8 * hw);
      float4 s3 = *reinterpret_cast<const float4*>(sa + 16 + 8 * hw + 4);
      Frag b3f0, b3f1;
      b3f0.i[0] = cvtpk(ssp_f(s0.x + t0.x), ssp_f(s0.y + t0.y));
      b3f0.i[1] = cvtpk(ssp_f(s0.z + t0.z), ssp_f(s0.w + t0.w));
      b3f0.i[2] = cvtpk(ssp_f(s1.x + t1.x), ssp_f(s1.y + t1.y));
      b3f0.i[3] = cvtpk(ssp_f(s1.z + t1.z), ssp_f(s1.w + t1.w));
      b3f1.i[0] = cvtpk(ssp_f(s2.x + t2.x), ssp_f(s2.y + t2.y));
      b3f1.i[1] = cvtpk(ssp_f(s2.z + t2.z), ssp_f(s2.w + t2.w));
      b3f1.i[2] = cvtpk(ssp_f(s3.x + t3.x), ssp_f(s3.y + t3.y));
      b3f1.i[3] = cvtpk(ssp_f(s3.z + t3.z), ssp_f(s3.w + t3.w));

      // ---- GEMM3: nodes^T[fo][a] ----
      f32x16 d3 = ld_bias16(biasC);
      d3 = mfma32(a3s0, b3f0, d3);
      d3 = mfma32(a3s1, b3f1, d3);

      // ---- out += em * gates ⊙ nodes ----
#pragma unroll
      for (int r = 0; r < 16; ++r) acc[r] = fmaf(em[t] * d2[r], d3[r], acc[r]);
    }

    // reduce over columns a (32 lanes within each half-wave)
#pragma unroll
    for (int m = 1; m <= 16; m <<= 1) {
#pragma unroll
      for (int r = 0; r < 16; ++r) acc[r] += __shfl_xor(acc[r], m, 64);
    }

    // rows for reg-quad q: 8q + 4hw + (0..3) -> contiguous float4
    if (col == 0) {
      float4* o = reinterpret_cast<float4*>(out + bp * NF);
#pragma unroll
      for (int q = 0; q < 4; ++q) {
        float4 v;
        v.x = acc[4 * q];     v.y = acc[4 * q + 1];
        v.z = acc[4 * q + 2]; v.w = acc[4 * q + 3];
        o[2 * q + hw] = v;
      }
    }
  }
}

extern "C" void kernel_launch(void* const* d_in, const int* in_sizes, int n_in,
                              void* d_out, int out_size, void* d_ws, size_t ws_size,
                              hipStream_t stream) {
  const float* scalar    = (const float*)d_in[0];
  const float* sreciever = (const float*)d_in[1];
  const float* expansion = (const float*)d_in[2];
  const float* maskp     = (const float*)d_in[3];
  const float* edist     = (const float*)d_in[4];
  const float* W1e       = (const float*)d_in[5];
  const float* b1e       = (const float*)d_in[6];
  const float* W2e       = (const float*)d_in[7];
  const float* b2e       = (const float*)d_in[8];
  const float* W1n       = (const float*)d_in[9];
  const float* b1n       = (const float*)d_in[10];
  const float* W2n       = (const float*)d_in[11];
  const float* b2n       = (const float*)d_in[12];
  float* out    = (float*)d_out;
  float* src_ws = (float*)d_ws;     // 192*32 floats = 24 KB

  prep_kernel<<<1048, 256, 0, stream>>>(scalar, sreciever, W1n, b1n, out, src_ws);
  // 1024 blocks * 4 waves * 2 bp = 8192 = NBP
  fused_main<<<NBP / 8, 256, 0, stream>>>(expansion, maskp, edist,
                                          W1e, b1e, W2e, b2e, W2n, b2n,
                                          src_ws, out);
}